// Round 10
// baseline (338.676 us; speedup 1.0000x reference)
//
#include <hip/hip_runtime.h>
#include <hip/hip_bf16.h>

// SeqAttention collapses algebraically:
//   alpha = softmax(e, axis=1); s = sum(alpha, axis=1)  ==>  s == 1 exactly
//   (softmax columns each sum to 1 over the axis being summed).
//   context[b,t] = sum_d hid[b,t,d] = x[b,t,:] . colsum(W) + sum(b)
// ws[0..D-1] = column sums of W, ws[D] = sum(b); out[row] = x[row,:].ws + ws[D].
//
// Kernel-side roofline: read x (256MB) + W (4MB), write 256KB -> ~42 us @ 6.3 TB/s.
// Measured total (R7: 335us) is dominated by harness reset fills (1GiB ws poison
// ~160us + ~78us input restore); controllable slice ~95us, floor ~48us.

constexpr int Dn = 1024;
constexpr int ROWS = 32 * 2048;   // 65536
constexpr int NWAVE = 8192;       // 2048 blocks x 4 waves; 8 rows per wave

typedef float v4f __attribute__((ext_vector_type(4)));

// ---- kernel 1 (fused): colsum(W) -> ws[0..1023], sum(b) -> ws[1024]. No atomics,
// no pre-zero needed: every ws element is written exactly once, non-atomically.
__global__ __launch_bounds__(256) void sa_prep_kernel(const float* __restrict__ W,
                                                      const float* __restrict__ bvec,
                                                      float* __restrict__ ws) {
    int blk = blockIdx.x;
    if (blk < 32) {
        // block owns 32 columns [32*blk, 32*blk+32) = 8 float4 slots per row
        int t  = threadIdx.x;
        int cq = t & 7;          // colquad 0..7 within slice
        int r0 = t >> 3;         // row phase 0..31
        const v4f* Wv = reinterpret_cast<const v4f*>(W);
        v4f acc = {0.f, 0.f, 0.f, 0.f};
        #pragma unroll 4
        for (int r = r0; r < Dn; r += 32) {
            acc += Wv[r * (Dn / 4) + blk * 8 + cq];
        }
        __shared__ v4f part[256];
        part[t] = acc;
        __syncthreads();
        if (t < 8) {             // t == colquad
            v4f s = {0.f, 0.f, 0.f, 0.f};
            #pragma unroll
            for (int i = 0; i < 32; ++i) s += part[t + i * 8];
            reinterpret_cast<v4f*>(ws)[blk * 8 + t] = s;
        }
    } else {
        // block 32: bsum
        int t = threadIdx.x;
        float a = bvec[t] + bvec[t + 256] + bvec[t + 512] + bvec[t + 768];
        #pragma unroll
        for (int off = 32; off; off >>= 1) a += __shfl_xor(a, off, 64);
        __shared__ float s4[4];
        if ((t & 63) == 0) s4[t >> 6] = a;
        __syncthreads();
        if (t == 0) ws[Dn] = s4[0] + s4[1] + s4[2] + s4[3];
    }
}

// ---- kernel 2: persistent waves, 8 rows each; ws fragment hoisted to registers ----
__global__ __launch_bounds__(256) void sa_dot_kernel(const float* __restrict__ x,
                                                     const float* __restrict__ ws,
                                                     float* __restrict__ out) {
    int wid  = (int)((blockIdx.x * 256u + threadIdx.x) >> 6);   // wave id 0..8191
    int lane = threadIdx.x & 63;

    // hoist the wcol fragment (16 floats/lane) + bsum into registers once
    const v4f* wr = reinterpret_cast<const v4f*>(ws);
    v4f w0 = wr[lane], w1 = wr[lane + 64], w2 = wr[lane + 128], w3 = wr[lane + 192];
    float bsum = ws[Dn];

    #pragma unroll
    for (int r = 0; r < 8; ++r) {
        int row = wid + r * NWAVE;        // consecutive waves -> consecutive rows
        const v4f* xr = reinterpret_cast<const v4f*>(x + (size_t)row * Dn);
        // x streamed exactly once (256MB >> L2): non-temporal
        v4f x0 = __builtin_nontemporal_load(&xr[lane]);
        v4f x1 = __builtin_nontemporal_load(&xr[lane + 64]);
        v4f x2 = __builtin_nontemporal_load(&xr[lane + 128]);
        v4f x3 = __builtin_nontemporal_load(&xr[lane + 192]);
        v4f p = x0 * w0 + x1 * w1 + x2 * w2 + x3 * w3;
        float acc = p.x + p.y + p.z + p.w;
        #pragma unroll
        for (int off = 32; off; off >>= 1) acc += __shfl_xor(acc, off, 64);
        if (lane == 0) out[row] = acc + bsum;
    }
}

extern "C" void kernel_launch(void* const* d_in, const int* in_sizes, int n_in,
                              void* d_out, int out_size, void* d_ws, size_t ws_size,
                              hipStream_t stream) {
    const float* x = (const float*)d_in[0];   // [B,T,D] fp32
    const float* W = (const float*)d_in[1];   // [D,D]  fp32
    const float* b = (const float*)d_in[2];   // [D]    fp32
    float* out = (float*)d_out;               // [B,T]  fp32
    float* ws  = (float*)d_ws;                // needs (D+1) floats = 4100 B

    sa_prep_kernel<<<33, 256, 0, stream>>>(W, b, ws);
    sa_dot_kernel<<<NWAVE / 4, 256, 0, stream>>>(x, ws, out);
}